// Round 9
// baseline (274.269 us; speedup 1.0000x reference)
//
#include <hip/hip_runtime.h>
#include <hip/hip_bf16.h>
#include <math.h>

#define B_   32
#define L_   512
#define C_   862
#define P_   720
#define H2_  1024
#define M_   (B_*C_)     // 27584 real rows
#define MP_  27648       // padded to multiple of 128
#define PP_  768         // P padded (zero rows 720..767)

typedef __hip_bfloat16 bf16;
typedef __attribute__((ext_vector_type(8))) short s16x8;
typedef __attribute__((ext_vector_type(4))) float f32x4;

__device__ __forceinline__ void gload_lds16(const bf16* g, bf16* lds) {
    __builtin_amdgcn_global_load_lds(
        (const __attribute__((address_space(1))) void*)g,
        (__attribute__((address_space(3))) void*)lds, 16, 0, 0);
}
__device__ __forceinline__ unsigned short f2b(float f) {
    bf16 h = __float2bfloat16(f);
    return *reinterpret_cast<unsigned short*>(&h);
}
__device__ __forceinline__ float b2f(unsigned short u) {
    return __uint_as_float((unsigned int)u << 16);
}

// ---------------------------------------------------------------- DCT matrix (bf16)
__global__ __launch_bounds__(256) void build_dct(bf16* __restrict__ D) {
    int idx = blockIdx.x * 256 + threadIdx.x;
    if (idx >= L_ * L_) return;
    int k = idx >> 9, l = idx & 511;
    double ang = M_PI * (double)((2 * l + 1) * k) / (2.0 * (double)L_);
    D[idx] = __float2bfloat16((float)(2.0 * cos(ang)));
}

__global__ __launch_bounds__(256) void cvt_bf16(const float* __restrict__ in,
                                                bf16* __restrict__ out, int n) {
    int i = blockIdx.x * 256 + threadIdx.x;
    if (i < n) out[i] = __float2bfloat16(in[i]);
}

// Wl (720,512) -> bf16 padded to (768,512) with zeros
__global__ __launch_bounds__(256) void cvt_wl_pad(const float* __restrict__ in,
                                                  bf16* __restrict__ out) {
    int i = blockIdx.x * 256 + threadIdx.x;
    if (i >= PP_ * L_) return;
    int r = i >> 9;
    out[i] = (r < P_) ? __float2bfloat16(in[i]) : __float2bfloat16(0.f);
}

// ---------------------------------------------------- x (B,L,C) -> Xc (B*C,L) bf16
__global__ __launch_bounds__(256) void transpose_x(const float* __restrict__ x,
                                                   bf16* __restrict__ Xc) {
    __shared__ float tile[32][33];
    int b  = blockIdx.z;
    int c0 = blockIdx.x * 32;
    int l0 = blockIdx.y * 32;
    int tx = threadIdx.x & 31, ty = threadIdx.x >> 5;
#pragma unroll
    for (int i = 0; i < 4; ++i) {
        int l = l0 + ty + i * 8, c = c0 + tx;
        float v = 0.f;
        if (l < L_ && c < C_) v = x[((size_t)b * L_ + l) * C_ + c];
        tile[ty + i * 8][tx] = v;
    }
    __syncthreads();
#pragma unroll
    for (int i = 0; i < 4; ++i) {
        int c = c0 + ty + i * 8, l = l0 + tx;
        if (c < C_ && l < L_)
            Xc[((size_t)b * C_ + c) * L_ + l] = __float2bfloat16(tile[tx][ty + i * 8]);
    }
}

// --------------------- row LayerNorm (512), wave-per-row, bf16 in -> bf16 out
template <bool MUL>
__global__ __launch_bounds__(256) void ln_rows(const bf16* __restrict__ X,
                                               const bf16* __restrict__ Xc,
                                               const float* __restrict__ gamma,
                                               const float* __restrict__ beta,
                                               bf16* __restrict__ Out) {
    int row  = blockIdx.x * 4 + (threadIdx.x >> 6);
    int lane = threadIdx.x & 63;
    const s16x8 v = *reinterpret_cast<const s16x8*>(X + (size_t)row * L_ + lane * 8);
    float f[8], s = 0.f, q = 0.f;
#pragma unroll
    for (int e = 0; e < 8; ++e) {
        f[e] = b2f((unsigned short)v[e]);
        s += f[e]; q += f[e] * f[e];
    }
#pragma unroll
    for (int off = 1; off < 64; off <<= 1) {
        s += __shfl_xor(s, off);
        q += __shfl_xor(q, off);
    }
    float mu = s * (1.f / L_);
    float rs = rsqrtf(q * (1.f / L_) - mu * mu + 1e-6f);
    float4 g0 = *reinterpret_cast<const float4*>(gamma + lane * 8);
    float4 g1 = *reinterpret_cast<const float4*>(gamma + lane * 8 + 4);
    float4 b0 = *reinterpret_cast<const float4*>(beta + lane * 8);
    float4 b1 = *reinterpret_cast<const float4*>(beta + lane * 8 + 4);
    float gg[8] = {g0.x, g0.y, g0.z, g0.w, g1.x, g1.y, g1.z, g1.w};
    float bb[8] = {b0.x, b0.y, b0.z, b0.w, b1.x, b1.y, b1.z, b1.w};
    float xm[8];
    if (MUL) {
        const s16x8 xv = *reinterpret_cast<const s16x8*>(Xc + (size_t)row * L_ + lane * 8);
#pragma unroll
        for (int e = 0; e < 8; ++e) xm[e] = b2f((unsigned short)xv[e]);
    }
    s16x8 o;
#pragma unroll
    for (int e = 0; e < 8; ++e) {
        float y = (f[e] - mu) * rs * gg[e] + bb[e];
        if (MUL) y *= xm[e];
        o[e] = (short)f2b(y);
    }
    *reinterpret_cast<s16x8*>(Out + (size_t)row * L_ + lane * 8) = o;
}

// ------------------------------------------------- bf16 MFMA NT GEMM, 128x64 tile
// High-TLP design: 4 waves (2M x 2N), wave = 64x32 (acc[4][2]), BK=64,
// SINGLE-buffered 24 KB LDS -> 6 blocks/CU; grids 1700-3500 blocks.
// Latency hidden by block-level TLP (5-6 co-resident blocks interleave their
// stage/drain/compute phases), not by in-block pipelining.
// Verified round-4 swizzle: 128 B LDS rows, read slot = granule ^ (row&7),
// staged by gload_lds with inverse-swizzled SOURCE, linear dest (rule #21).
// OUTMODE 0: bf16 linear [m][ldc] (ACT 0 none / 1 relu / 2 sigmoid)
// OUTMODE 1: f32 scatter out[b][m][c] (n = flat (b,c)) + bias[m]  (operand-swapped D)
template <int ACT, int OUTMODE>
__global__ __launch_bounds__(256, 5)
void gemm4(const bf16* __restrict__ A, int lda,
           const bf16* __restrict__ Bm, int ldb,
           const float* __restrict__ bias, void* __restrict__ Cout, int ldc,
           int K, int Mreal, int Nreal) {
    constexpr int BK = 64;
    __shared__ __align__(16) bf16 As[128][BK];   // 16 KB
    __shared__ __align__(16) bf16 Bs[64][BK];    //  8 KB
    int tid = threadIdx.x, w = tid >> 6, lane = tid & 63;
    int wm = w >> 1, wn = w & 1;                 // 2x2 waves, wave tile 64x32
    size_t bm = (size_t)blockIdx.y * 128;
    size_t bn = (size_t)blockIdx.x * 64;
    const bf16* Ab = A + bm * lda;
    const bf16* Bb = Bm + bn * ldb;

    // staging: one gload_lds16 covers 8 rows of 128 B.
    // lane -> row lrow = lane>>3, granule lslot = lane&7; source inverse-swizzled.
    int lrow  = lane >> 3;
    int srck  = ((lane & 7) ^ lrow) << 3;        // element offset in BK row

    f32x4 acc[4][2] = {};
    int fr = lane & 15, kq = lane >> 4;

    const int NT = K / BK;
    for (int t = 0; t < NT; ++t) {
        int k0 = t * BK;
        // wave w stages A rows [w*32, w*32+32) (4 instr) + B rows [w*16, w*16+16) (2)
#pragma unroll
        for (int i = 0; i < 4; ++i)
            gload_lds16(Ab + (size_t)(w * 32 + i * 8 + lrow) * lda + k0 + srck,
                        &As[w * 32 + i * 8][0]);
#pragma unroll
        for (int i = 0; i < 2; ++i)
            gload_lds16(Bb + (size_t)(w * 16 + i * 8 + lrow) * ldb + k0 + srck,
                        &Bs[w * 16 + i * 8][0]);
        __syncthreads();   // vmcnt(0)+barrier: tile staged

#pragma unroll
        for (int t2 = 0; t2 < 2; ++t2) {
            s16x8 av[4], bv[2];
#pragma unroll
            for (int i = 0; i < 4; ++i) {
                int row = wm * 64 + i * 16 + fr;
                int slot = ((t2 << 2) + kq) ^ (fr & 7);
                av[i] = *reinterpret_cast<const s16x8*>((const char*)&As[0][0] + row * 128 + (slot << 4));
            }
#pragma unroll
            for (int j = 0; j < 2; ++j) {
                int row = wn * 32 + j * 16 + fr;
                int slot = ((t2 << 2) + kq) ^ (fr & 7);
                bv[j] = *reinterpret_cast<const s16x8*>((const char*)&Bs[0][0] + row * 128 + (slot << 4));
            }
#pragma unroll
            for (int i = 0; i < 4; ++i)
#pragma unroll
                for (int j = 0; j < 2; ++j)
                    acc[i][j] = __builtin_amdgcn_mfma_f32_16x16x32_bf16(av[i], bv[j], acc[i][j], 0, 0, 0);
        }
        __syncthreads();   // reads done before next stage overwrites
    }

    if (OUTMODE == 0) {
        bf16* C = (bf16*)Cout;
#pragma unroll
        for (int i = 0; i < 4; ++i) {
#pragma unroll
            for (int r = 0; r < 4; ++r) {
                int m = (int)bm + wm * 64 + i * 16 + kq * 4 + r;
                if (m >= Mreal) continue;
#pragma unroll
                for (int j = 0; j < 2; ++j) {
                    int n = (int)bn + wn * 32 + j * 16 + fr;
                    if (n >= Nreal) continue;
                    float v = acc[i][j][r];
                    if (ACT == 1) v = fmaxf(v, 0.f);
                    if (ACT == 2) v = 1.f / (1.f + __expf(-v));
                    C[(size_t)m * ldc + n] = __float2bfloat16(v);
                }
            }
        }
    } else {
        float* O = (float*)Cout;
#pragma unroll
        for (int j = 0; j < 2; ++j) {
            int n = (int)bn + wn * 32 + j * 16 + fr;
            if (n >= Nreal) continue;
            int sb = n / C_, sc = n - sb * C_;
#pragma unroll
            for (int i = 0; i < 4; ++i) {
#pragma unroll
                for (int r = 0; r < 4; ++r) {
                    int m = (int)bm + wm * 64 + i * 16 + kq * 4 + r;
                    if (m >= Mreal) continue;
                    O[(size_t)sb * (P_ * C_) + (size_t)m * C_ + sc] = acc[i][j][r] + bias[m];
                }
            }
        }
    }
}

extern "C" void kernel_launch(void* const* d_in, const int* in_sizes, int n_in,
                              void* d_out, int out_size, void* d_ws, size_t ws_size,
                              hipStream_t stream) {
    const float* x     = (const float*)d_in[0];
    const float* W1    = (const float*)d_in[1];
    const float* W2    = (const float*)d_in[2];
    const float* gamma = (const float*)d_in[3];
    const float* beta  = (const float*)d_in[4];
    const float* Wl    = (const float*)d_in[5];
    const float* bl    = (const float*)d_in[6];
    float* out = (float*)d_out;

    bf16* ws   = (bf16*)d_ws;
    bf16* Xc   = ws;                           // MP_ x 512
    bf16* Fq   = Xc + (size_t)MP_ * L_;        // MP_ x 512 (freq, later fw)
    bf16* Fn   = Fq + (size_t)MP_ * L_;        // MP_ x 512 (Fn, later Prod)
    bf16* Hb   = Fn + (size_t)MP_ * L_;        // MP_ x 1024
    bf16* Dbf  = Hb + (size_t)MP_ * H2_;       // 512 x 512
    bf16* W1bf = Dbf + (size_t)L_ * L_;        // 1024 x 512
    bf16* W2bf = W1bf + (size_t)H2_ * L_;      // 512 x 1024
    bf16* Wlbf = W2bf + (size_t)L_ * H2_;      // 768 x 512 (zero-padded)

    build_dct<<<(L_ * L_ + 255) / 256, 256, 0, stream>>>(Dbf);
    cvt_bf16<<<(H2_ * L_ + 255) / 256, 256, 0, stream>>>(W1, W1bf, H2_ * L_);
    cvt_bf16<<<(L_ * H2_ + 255) / 256, 256, 0, stream>>>(W2, W2bf, L_ * H2_);
    cvt_wl_pad<<<(PP_ * L_ + 255) / 256, 256, 0, stream>>>(Wl, Wlbf);
    transpose_x<<<dim3((C_ + 31) / 32, (L_ + 31) / 32, B_), 256, 0, stream>>>(x, Xc);

    // Stage A: freq = Xc . D^T  (bf16 out)   grid 8 x 216 = 1728 blocks
    gemm4<0, 0><<<dim3(L_ / 64, MP_ / 128), 256, 0, stream>>>(
        Xc, L_, Dbf, L_, nullptr, Fq, L_, L_, M_, L_);
    ln_rows<false><<<M_ / 4, 256, 0, stream>>>(Fq, nullptr, gamma, beta, Fn);

    // Stage B: H = relu(Fn . W1^T)  (bf16 out)   grid 16 x 216 = 3456 blocks
    gemm4<1, 0><<<dim3(H2_ / 64, MP_ / 128), 256, 0, stream>>>(
        Fn, L_, W1bf, L_, nullptr, Hb, H2_, L_, M_, H2_);

    // Stage C: fw = sigmoid(H . W2^T)  (bf16 out, K=1024)   grid 8 x 216
    gemm4<2, 0><<<dim3(L_ / 64, MP_ / 128), 256, 0, stream>>>(
        Hb, H2_, W2bf, H2_, nullptr, Fq, L_, H2_, M_, L_);
    // Prod = LN(fw) * Xc
    ln_rows<true><<<M_ / 4, 256, 0, stream>>>(Fq, Xc, gamma, beta, Fn);

    // Stage D (operand-swapped): out[b,p,c] = Wl[p,:].Prod[(b,c),:] + bl[p]
    // grid 432 x 6 = 2592 blocks
    gemm4<0, 1><<<dim3(MP_ / 64, PP_ / 128), 256, 0, stream>>>(
        Wlbf, L_, Fn, L_, bl, out, 0, L_, P_, M_);
}